// Round 5
// baseline (1125.499 us; speedup 1.0000x reference)
//
#include <hip/hip_runtime.h>
#include <math.h>

#define TLEN 256
#define BATCH 4
#define DMODEL 768
#define DINNER 1536
#define NSTATE 16
#define DTRANK 48
#define NLAYER 4
#define NTOK 1024

#define S_IP 2359296
#define S_OP 1179648
#define S_XP2 196608            /* 128 x 1536 zero-padded */
#define WL (S_IP + S_OP + S_XP2) /* 3735552 per-layer bf16 weight block */

typedef __bf16 bf16x8 __attribute__((ext_vector_type(8)));
typedef float f32x4 __attribute__((ext_vector_type(4)));

__device__ inline unsigned short f2b(float f) {
    union { float f; unsigned u; } v;
    v.f = f;
    unsigned r = (v.u + 0x7fffu + ((v.u >> 16) & 1u)) >> 16;  // RNE
    return (unsigned short)r;
}

__device__ inline void gload16(const void* g, void* l) {
    __builtin_amdgcn_global_load_lds(
        (const __attribute__((address_space(1))) void*)g,
        (__attribute__((address_space(3))) void*)l, 16, 0, 0);
}

// ---------------- embed: f32 x + bf16 xb ----------------
__global__ __launch_bounds__(256) void embed_k(const int* __restrict__ ids,
                                               const float* __restrict__ emb,
                                               const float* __restrict__ pos,
                                               float* __restrict__ x,
                                               unsigned short* __restrict__ xb) {
    int idx = blockIdx.x * 256 + threadIdx.x;
    int d = idx % DMODEL;
    int bt = idx / DMODEL;
    int t = bt % TLEN;
    float v = emb[(size_t)ids[bt] * DMODEL + d] + pos[t * DMODEL + d];
    x[idx] = v;
    xb[idx] = f2b(v);
}

// ---------------- all-layer weight convert (ip, op, xp-pad128) ----------------
__global__ __launch_bounds__(256) void wconv_k(const float* __restrict__ ipw,
                                               const float* __restrict__ opw,
                                               const float* __restrict__ xpw,
                                               unsigned short* __restrict__ w_all) {
    int l = blockIdx.y;
    int i4 = (blockIdx.x * 256 + threadIdx.x) * 4;
    unsigned short* wl = w_all + (size_t)l * WL;
    if (i4 < S_IP) {
        float4 v = *(const float4*)(ipw + (size_t)l * S_IP + i4);
        ushort4 o; o.x = f2b(v.x); o.y = f2b(v.y); o.z = f2b(v.z); o.w = f2b(v.w);
        *(ushort4*)(wl + i4) = o;
    } else if (i4 < S_IP + S_OP) {
        int i = i4 - S_IP;
        float4 v = *(const float4*)(opw + (size_t)l * S_OP + i);
        ushort4 o; o.x = f2b(v.x); o.y = f2b(v.y); o.z = f2b(v.z); o.w = f2b(v.w);
        *(ushort4*)(wl + S_IP + i) = o;
    } else {
        int i = i4 - S_IP - S_OP;
        int r = i / 1536, k = i % 1536;
        ushort4 o = {0, 0, 0, 0};
        if (r < 80) {
            float4 v = *(const float4*)(xpw + (size_t)l * (80 * 1536) + (size_t)r * 1536 + k);
            o.x = f2b(v.x); o.y = f2b(v.y); o.z = f2b(v.z); o.w = f2b(v.w);
        }
        *(ushort4*)(wl + S_IP + S_OP + i) = o;
    }
}

// ---------------- bf16 MFMA GEMM, 2-phase LDS double-buffer pipeline ----------------
// D[row][col] = sum_k A[row,k]*B[col,k]; A,B bf16 row-major (k contiguous).
// MODE 0: o0 = xzT [3072][1024] f32 (rows=e, cols=tok)            (in_proj)
// MODE 1: o0 = xdblT [80][1024] f32, store rows<80 only           (x_proj)
// MODE 3: o0 = x [1024][768] f32 accumulate, o1 = xb bf16         (out_proj)
template <int BM, int MODE>
__global__ __launch_bounds__(256) void mgemm_k(const unsigned short* __restrict__ A, int lda,
                                               const unsigned short* __restrict__ B, int ldb,
                                               int K,
                                               float* __restrict__ o0,
                                               unsigned short* __restrict__ o1) {
    constexpr int MI = BM / 32;
    __shared__ __align__(16) unsigned short Ab[2][BM * 64];
    __shared__ __align__(16) unsigned short Bb[2][64 * 64];

    int tid = threadIdx.x;
    int lane = tid & 63;
    int wave = tid >> 6;
    int wm = (wave >> 1) * (BM / 2);
    int wn = (wave & 1) * 32;
    int bm = blockIdx.x * BM;
    int bn = blockIdx.y * 64;
    int fr = lane & 15;
    int fq = lane >> 4;
    int fk = fq * 8;
    int srow = lane >> 3;        // 0..7
    int scol = (lane & 7) * 8;   // 0..56 (elems)

    f32x4 acc[MI][2] = {};

    auto stage = [&](int s, int k0) {
#pragma unroll
        for (int c = 0; c < BM / 32; ++c) {   // A: 8 rows per gload, BM/4 rows/wave
            int r = wave * (BM / 4) + c * 8;
            gload16(A + (size_t)(bm + r + srow) * lda + k0 + scol, &Ab[s][r * 64]);
        }
#pragma unroll
        for (int c = 0; c < 2; ++c) {         // B: 16 rows per wave
            int r = wave * 16 + c * 8;
            gload16(B + (size_t)(bn + r + srow) * ldb + k0 + scol, &Bb[s][r * 64]);
        }
    };

    int nk = K >> 6;
    stage(0, 0);
    asm volatile("s_waitcnt vmcnt(0)" ::: "memory");
    __builtin_amdgcn_s_barrier();

    for (int t = 0; t < nk; ++t) {
        int cur = t & 1;
        if (t + 1 < nk) stage(cur ^ 1, (t + 1) * 64);
#pragma unroll
        for (int ks = 0; ks < 2; ++ks) {
            int kk = ks * 32 + fk;
            bf16x8 af[MI], bfr[2];
#pragma unroll
            for (int i = 0; i < MI; ++i)
                af[i] = *(const bf16x8*)&Ab[cur][(wm + i * 16 + fr) * 64 + kk];
#pragma unroll
            for (int j = 0; j < 2; ++j)
                bfr[j] = *(const bf16x8*)&Bb[cur][(wn + j * 16 + fr) * 64 + kk];
#pragma unroll
            for (int i = 0; i < MI; ++i)
#pragma unroll
                for (int j = 0; j < 2; ++j)
                    acc[i][j] = __builtin_amdgcn_mfma_f32_16x16x32_bf16(
                        af[i], bfr[j], acc[i][j], 0, 0, 0);
        }
        asm volatile("s_waitcnt vmcnt(0)" ::: "memory");
        __builtin_amdgcn_s_barrier();
    }

#pragma unroll
    for (int i = 0; i < MI; ++i) {
#pragma unroll
        for (int j = 0; j < 2; ++j) {
            int lc = wn + j * 16 + fr;   // local col
#pragma unroll
            for (int q = 0; q < 4; ++q) {
                int lr = wm + i * 16 + fq * 4 + q;   // local row
                float v = acc[i][j][q];
                if (MODE == 0) {
                    o0[(size_t)(bm + lr) * NTOK + bn + lc] = v;
                } else if (MODE == 1) {
                    int f = bm + lr;
                    if (f < 80) o0[(size_t)f * NTOK + bn + lc] = v;
                } else {  // MODE 3: residual accumulate + bf16 mirror
                    size_t idx = (size_t)(bm + lr) * DMODEL + bn + lc;
                    float nv = o0[idx] + v;
                    o0[idx] = nv;
                    o1[idx] = f2b(nv);
                }
            }
        }
    }
}

// ---------------- causal dwconv(K=4) + bias + SiLU ----------------
__global__ __launch_bounds__(256) void conv_k(const float* __restrict__ xzT,
                                              const float* __restrict__ cw,
                                              const float* __restrict__ cb,
                                              float* __restrict__ xiT,
                                              unsigned short* __restrict__ xib) {
    __shared__ unsigned short tile[4][256];
    int tid = threadIdx.x;
    int ch = tid >> 6;
    int d = blockIdx.x * 4 + ch;
    int b = blockIdx.y;
    int t0 = (tid & 63) * 4;
    const float* src = xzT + (size_t)d * NTOK + b * TLEN + t0;
    float4 cur = *(const float4*)src;
    float4 prev = {0.f, 0.f, 0.f, 0.f};
    if (t0 > 0) prev = *(const float4*)(src - 4);
    float w0 = cw[d * 4 + 0], w1 = cw[d * 4 + 1], w2 = cw[d * 4 + 2], w3 = cw[d * 4 + 3];
    float bb = cb[d];
    float xw[8] = {prev.x, prev.y, prev.z, prev.w, cur.x, cur.y, cur.z, cur.w};
    float4 r;
#pragma unroll
    for (int u = 0; u < 4; ++u) {
        float s = bb + w0 * xw[u + 1] + w1 * xw[u + 2] + w2 * xw[u + 3] + w3 * xw[u + 4];
        float v = s / (1.f + __expf(-s));
        ((float*)&r)[u] = v;
        tile[ch][t0 + u] = f2b(v);
    }
    *(float4*)(xiT + (size_t)d * NTOK + b * TLEN + t0) = r;
    __syncthreads();
    int t = tid;
    ushort4 o;
    o.x = tile[0][t]; o.y = tile[1][t]; o.z = tile[2][t]; o.w = tile[3][t];
    *(ushort4*)(xib + (size_t)(b * TLEN + t) * DINNER + blockIdx.x * 4) = o;
}

// ---------------- selective scan + fused dt_proj(softplus) ----------------
// grid (DINNER/4 = 384, BATCH); 4 waves = 4 time-chunks; wave: 4 chains x 16 states.
__global__ __launch_bounds__(256) void scan_k(const float* __restrict__ xiT,
                                              const float* __restrict__ xzT,
                                              const float* __restrict__ xdblT,
                                              const float* __restrict__ dpw,
                                              const float* __restrict__ dpb,
                                              const float* __restrict__ Alog,
                                              const float* __restrict__ Dsk,
                                              unsigned short* __restrict__ ybb) {
    __shared__ float dt_s[4][260];
    __shared__ float yl[4][260];
    __shared__ float cum[4][260];
    __shared__ float wdt[192];
    __shared__ float hL[4][4][16];
    __shared__ float Pb[4][4][16];
    __shared__ float Hin[4][4][16];

    int tid = threadIdx.x;
    int c = tid >> 6;
    int lane = tid & 63;
    int ch = lane >> 4;
    int n = lane & 15;
    int d0 = blockIdx.x * 4;
    int d = d0 + ch;
    int b = blockIdx.y;
    int tl0 = c * 64;

    // --- fused dt_proj: dt[d][t] = softplus(xdbl[t,0:48]·dpw[d] + dpb[d]) in f32
    if (tid < 192) wdt[tid] = dpw[(size_t)d0 * DTRANK + tid];  // 4 rows contiguous
    __syncthreads();
    {
        int ch2 = tid >> 6;
        int t4 = (tid & 63) * 4;
        const float* wrow = &wdt[ch2 * DTRANK];
        f32x4 accd = {0.f, 0.f, 0.f, 0.f};
#pragma unroll
        for (int r = 0; r < DTRANK; ++r) {
            float4 xv = *(const float4*)(xdblT + (size_t)r * NTOK + b * TLEN + t4);
            float w = wrow[r];
            accd[0] += w * xv.x; accd[1] += w * xv.y;
            accd[2] += w * xv.z; accd[3] += w * xv.w;
        }
        float bias = dpb[d0 + ch2];
#pragma unroll
        for (int u = 0; u < 4; ++u) {
            float v = accd[u] + bias;
            v = (v > 0.f) ? v + log1pf(__expf(-v)) : log1pf(__expf(v));
            dt_s[ch2][t4 + u] = v;
        }
    }
    __syncthreads();

    float a = -__expf(Alog[(size_t)d * NSTATE + n]);
    const float* xip = xiT + (size_t)d * NTOK + b * TLEN + tl0;
    const float* Bp = xdblT + (size_t)(DTRANK + n) * NTOK + b * TLEN + tl0;
    const float* Cp = xdblT + (size_t)(DTRANK + NSTATE + n) * NTOK + b * TLEN + tl0;

    float h = 0.f, cd = 0.f;
    for (int t8 = 0; t8 < 64; t8 += 8) {
        float4 x0 = *(const float4*)(xip + t8), x1 = *(const float4*)(xip + t8 + 4);
        float4 B0 = *(const float4*)(Bp + t8), B1 = *(const float4*)(Bp + t8 + 4);
        float4 C0 = *(const float4*)(Cp + t8), C1 = *(const float4*)(Cp + t8 + 4);
        float xis[8] = {x0.x, x0.y, x0.z, x0.w, x1.x, x1.y, x1.z, x1.w};
        float Bs[8] = {B0.x, B0.y, B0.z, B0.w, B1.x, B1.y, B1.z, B1.w};
        float Cs[8] = {C0.x, C0.y, C0.z, C0.w, C1.x, C1.y, C1.z, C1.w};
#pragma unroll
        for (int u = 0; u < 8; ++u) {
            float dtv = dt_s[ch][tl0 + t8 + u];
            cd += dtv;
            float dA = __expf(dtv * a);
            h = dA * h + (dtv * xis[u]) * Bs[u];
            float p = h * Cs[u];
            p += __shfl_xor(p, 1);
            p += __shfl_xor(p, 2);
            p += __shfl_xor(p, 4);
            p += __shfl_xor(p, 8);
            if (n == 0) {
                yl[ch][tl0 + t8 + u] = p;
                cum[ch][tl0 + t8 + u] = cd;
            }
        }
    }
    hL[c][ch][n] = h;
    Pb[c][ch][n] = __expf(a * cd);
    __syncthreads();
    if (c == 0) {
        float H = 0.f;
        Hin[0][ch][n] = 0.f;
#pragma unroll
        for (int cc = 1; cc < 4; ++cc) {
            H = Pb[cc - 1][ch][n] * H + hL[cc - 1][ch][n];
            Hin[cc][ch][n] = H;
        }
    }
    __syncthreads();
    float Hv = Hin[c][ch][n];
    float Dv = Dsk[d];
    const float* zp = xzT + (size_t)(DINNER + d) * NTOK + b * TLEN + tl0;
    for (int t8 = 0; t8 < 64; t8 += 8) {
        float4 C0 = *(const float4*)(Cp + t8), C1 = *(const float4*)(Cp + t8 + 4);
        float4 x0 = *(const float4*)(xip + t8), x1 = *(const float4*)(xip + t8 + 4);
        float4 z0 = *(const float4*)(zp + t8), z1 = *(const float4*)(zp + t8 + 4);
        float Cs[8] = {C0.x, C0.y, C0.z, C0.w, C1.x, C1.y, C1.z, C1.w};
        float xis[8] = {x0.x, x0.y, x0.z, x0.w, x1.x, x1.y, x1.z, x1.w};
        float zs[8] = {z0.x, z0.y, z0.z, z0.w, z1.x, z1.y, z1.z, z1.w};
#pragma unroll
        for (int u = 0; u < 8; ++u) {
            float cdt = cum[ch][tl0 + t8 + u];
            float corr = Cs[u] * __expf(a * cdt) * Hv;
            corr += __shfl_xor(corr, 1);
            corr += __shfl_xor(corr, 2);
            corr += __shfl_xor(corr, 4);
            corr += __shfl_xor(corr, 8);
            if (n == 0) {
                float y = yl[ch][tl0 + t8 + u] + corr + Dv * xis[u];
                float zz = zs[u];
                y *= zz / (1.f + __expf(-zz));
                yl[ch][tl0 + t8 + u] = y;
            }
        }
    }
    __syncthreads();
    {
        int t = tid;
        ushort4 o;
        o.x = f2b(yl[0][t]);
        o.y = f2b(yl[1][t]);
        o.z = f2b(yl[2][t]);
        o.w = f2b(yl[3][t]);
        *(ushort4*)(ybb + (size_t)(b * TLEN + t) * DINNER + blockIdx.x * 4) = o;
    }
}

// ---------------- RMSNorm ----------------
__global__ __launch_bounds__(256) void rmsnorm_k(const float* __restrict__ x,
                                                 const float* __restrict__ nw,
                                                 float* __restrict__ out) {
    int row = blockIdx.x;
    const float* xr = x + (size_t)row * DMODEL;
    int tid = threadIdx.x;
    float s = 0.f;
    for (int d = tid; d < DMODEL; d += 256) {
        float v = xr[d];
        s += v * v;
    }
#pragma unroll
    for (int off = 32; off >= 1; off >>= 1) s += __shfl_down(s, off);
    __shared__ float red[4];
    __shared__ float scale;
    int wid = tid >> 6, lane = tid & 63;
    if (lane == 0) red[wid] = s;
    __syncthreads();
    if (tid == 0) {
        float tot = red[0] + red[1] + red[2] + red[3];
        scale = rsqrtf(tot / (float)DMODEL + 1e-5f);
    }
    __syncthreads();
    float sc = scale;
    for (int d = tid; d < DMODEL; d += 256)
        out[(size_t)row * DMODEL + d] = xr[d] * sc * nw[d];
}

extern "C" void kernel_launch(void* const* d_in, const int* in_sizes, int n_in,
                              void* d_out, int out_size, void* d_ws, size_t ws_size,
                              hipStream_t stream) {
    const int* ids = (const int*)d_in[0];
    const float* emb = (const float*)d_in[1];
    const float* pos = (const float*)d_in[2];
    const float* ipw = (const float*)d_in[3];
    const float* cw = (const float*)d_in[4];
    const float* cb = (const float*)d_in[5];
    const float* xpw = (const float*)d_in[6];
    const float* dpw = (const float*)d_in[7];
    const float* dpb = (const float*)d_in[8];
    const float* Alog = (const float*)d_in[9];
    const float* Dsk = (const float*)d_in[10];
    const float* opw = (const float*)d_in[11];
    const float* nw = (const float*)d_in[12];

    float* x = (float*)d_ws;                   // 786432
    float* xzT = x + 786432;                   // 3145728
    float* xiT = xzT + 3145728;                // 1572864
    float* xdblT = xiT + 1572864;              // 81920
    unsigned short* xb = (unsigned short*)(xdblT + 81920);  // 786432
    unsigned short* xib = xb + 786432;         // 1572864
    unsigned short* ybb = xib + 1572864;       // 1572864
    unsigned short* w_all = ybb + 1572864;     // 4 * WL

    // all-layer weight convert (one dispatch)
    wconv_k<<<dim3(WL / 1024, NLAYER), 256, 0, stream>>>(ipw, opw, xpw, w_all);
    embed_k<<<NTOK * DMODEL / 256, 256, 0, stream>>>(ids, emb, pos, x, xb);

    for (int l = 0; l < NLAYER; ++l) {
        const unsigned short* w_ip = w_all + (size_t)l * WL;
        const unsigned short* w_op = w_ip + S_IP;
        const unsigned short* w_xp = w_op + S_OP;
        const float* cw_l = cw + (size_t)l * DINNER * 4;
        const float* cb_l = cb + (size_t)l * DINNER;
        const float* dpw_l = dpw + (size_t)l * DINNER * DTRANK;
        const float* dpb_l = dpb + (size_t)l * DINNER;
        const float* Alog_l = Alog + (size_t)l * DINNER * NSTATE;
        const float* Dsk_l = Dsk + (size_t)l * DINNER;

        // in_proj: xzT[e][tok]
        mgemm_k<128, 0><<<dim3(3072 / 128, NTOK / 64), 256, 0, stream>>>(
            w_ip, DMODEL, xb, DMODEL, DMODEL, xzT, nullptr);
        // conv + silu -> xiT f32, xib bf16
        conv_k<<<dim3(DINNER / 4, BATCH), 256, 0, stream>>>(xzT, cw_l, cb_l, xiT, xib);
        // x_proj: xdblT [80][1024] f32 (rows 0..47 dt-feats, 48..63 B, 64..79 C)
        mgemm_k<64, 1><<<dim3(2, NTOK / 64), 256, 0, stream>>>(
            w_xp, DINNER, xib, DINNER, DINNER, xdblT, nullptr);
        // scan (+fused dt_proj)
        scan_k<<<dim3(DINNER / 4, BATCH), 256, 0, stream>>>(
            xiT, xzT, xdblT, dpw_l, dpb_l, Alog_l, Dsk_l, ybb);
        // out_proj: x += y @ opw^T, xb = bf16(x)
        mgemm_k<128, 3><<<dim3(NTOK / 128, DMODEL / 64), 256, 0, stream>>>(
            ybb, DINNER, w_op, DINNER, DINNER, x, xb);
    }

    rmsnorm_k<<<NTOK, 256, 0, stream>>>(x, nw, (float*)d_out);
}

// Round 6
// 603.666 us; speedup vs baseline: 1.8644x; 1.8644x over previous
//
#include <hip/hip_runtime.h>
#include <math.h>

#define TLEN 256
#define BATCH 4
#define DMODEL 768
#define DINNER 1536
#define NSTATE 16
#define DTRANK 48
#define NLAYER 4
#define NTOK 1024

#define S_IP 2359296
#define S_OP 1179648
#define S_XP2 196608            /* 128 x 1536 zero-padded */
#define S_DT 98304              /* 1536 x 64 zero-padded  */
#define WL (S_IP + S_OP + S_XP2 + S_DT)

typedef __bf16 bf16x8 __attribute__((ext_vector_type(8)));
typedef float f32x4 __attribute__((ext_vector_type(4)));

__device__ inline unsigned short f2b(float f) {
    union { float f; unsigned u; } v;
    v.f = f;
    unsigned r = (v.u + 0x7fffu + ((v.u >> 16) & 1u)) >> 16;  // RNE
    return (unsigned short)r;
}

__device__ inline void gload16(const void* g, void* l) {
    __builtin_amdgcn_global_load_lds(
        (const __attribute__((address_space(1))) void*)g,
        (__attribute__((address_space(3))) void*)l, 16, 0, 0);
}

// ---------------- embed: f32 x + bf16 xb ----------------
__global__ __launch_bounds__(256) void embed_k(const int* __restrict__ ids,
                                               const float* __restrict__ emb,
                                               const float* __restrict__ pos,
                                               float* __restrict__ x,
                                               unsigned short* __restrict__ xb) {
    int idx = blockIdx.x * 256 + threadIdx.x;
    int d = idx % DMODEL;
    int bt = idx / DMODEL;
    int t = bt % TLEN;
    float v = emb[(size_t)ids[bt] * DMODEL + d] + pos[t * DMODEL + d];
    x[idx] = v;
    xb[idx] = f2b(v);
}

// ---------------- all-layer weight convert (ip, op, xp-pad128, dt-pad64) ----------------
__global__ __launch_bounds__(256) void wconv_k(const float* __restrict__ ipw,
                                               const float* __restrict__ opw,
                                               const float* __restrict__ xpw,
                                               const float* __restrict__ dpw,
                                               unsigned short* __restrict__ w_all) {
    int l = blockIdx.y;
    int i4 = (blockIdx.x * 256 + threadIdx.x) * 4;
    unsigned short* wl = w_all + (size_t)l * WL;
    if (i4 < S_IP) {
        float4 v = *(const float4*)(ipw + (size_t)l * S_IP + i4);
        ushort4 o; o.x = f2b(v.x); o.y = f2b(v.y); o.z = f2b(v.z); o.w = f2b(v.w);
        *(ushort4*)(wl + i4) = o;
    } else if (i4 < S_IP + S_OP) {
        int i = i4 - S_IP;
        float4 v = *(const float4*)(opw + (size_t)l * S_OP + i);
        ushort4 o; o.x = f2b(v.x); o.y = f2b(v.y); o.z = f2b(v.z); o.w = f2b(v.w);
        *(ushort4*)(wl + S_IP + i) = o;
    } else if (i4 < S_IP + S_OP + S_XP2) {
        int i = i4 - S_IP - S_OP;
        int r = i / 1536, k = i % 1536;
        ushort4 o = {0, 0, 0, 0};
        if (r < 80) {
            float4 v = *(const float4*)(xpw + (size_t)l * (80 * 1536) + (size_t)r * 1536 + k);
            o.x = f2b(v.x); o.y = f2b(v.y); o.z = f2b(v.z); o.w = f2b(v.w);
        }
        *(ushort4*)(wl + S_IP + S_OP + i) = o;
    } else {
        int i = i4 - S_IP - S_OP - S_XP2;
        int r = i >> 6, k = i & 63;
        ushort4 o = {0, 0, 0, 0};
        if (k < DTRANK) {
            float4 v = *(const float4*)(dpw + (size_t)l * (DINNER * DTRANK) + (size_t)r * DTRANK + k);
            o.x = f2b(v.x); o.y = f2b(v.y); o.z = f2b(v.z); o.w = f2b(v.w);
        }
        *(ushort4*)(wl + S_IP + S_OP + S_XP2 + i) = o;
    }
}

// ---------------- bf16 MFMA GEMM, 2-phase LDS double-buffer pipeline ----------------
// D[row][col] = sum_k A[row,k]*B[col,k]; A,B bf16 row-major (k contiguous).
// MODE 0: o0 = xzT [3072][1024] f32 (rows=e, cols=tok)                  (in_proj)
// MODE 1: o0 = xdblT [80][1024] f32 (rows<80); o1 = xdblb bf16 [1024][64]
//         via LDS transpose, bm==0 blocks only                          (x_proj)
// MODE 2: o0 = dtT [1536][1024] f32, softplus(v + bias[row])            (dt_proj)
// MODE 3: o0 = x [1024][768] f32 accumulate, o1 = xb bf16 mirror        (out_proj)
template <int BM, int MODE>
__global__ __launch_bounds__(256) void mgemm_k(const unsigned short* __restrict__ A, int lda,
                                               const unsigned short* __restrict__ B, int ldb,
                                               int K,
                                               const float* __restrict__ bias,
                                               float* __restrict__ o0,
                                               unsigned short* __restrict__ o1) {
    constexpr int MI = BM / 32;
    __shared__ __align__(16) unsigned short Ab[2][BM * 64];
    __shared__ __align__(16) unsigned short Bb[2][64 * 64];
    __shared__ float Tt[(MODE == 1) ? 64 * 64 : 1];

    int tid = threadIdx.x;
    int lane = tid & 63;
    int wave = tid >> 6;
    int wm = (wave >> 1) * (BM / 2);
    int wn = (wave & 1) * 32;
    int bm = blockIdx.x * BM;
    int bn = blockIdx.y * 64;
    int fr = lane & 15;
    int fq = lane >> 4;
    int fk = fq * 8;
    int srow = lane >> 3;        // 0..7
    int scol = (lane & 7) * 8;   // 0..56 (elems)

    f32x4 acc[MI][2] = {};

    auto stage = [&](int s, int k0) {
#pragma unroll
        for (int c = 0; c < BM / 32; ++c) {   // A: 8 rows per gload
            int r = wave * (BM / 4) + c * 8;
            gload16(A + (size_t)(bm + r + srow) * lda + k0 + scol, &Ab[s][r * 64]);
        }
#pragma unroll
        for (int c = 0; c < 2; ++c) {         // B: 16 rows per wave
            int r = wave * 16 + c * 8;
            gload16(B + (size_t)(bn + r + srow) * ldb + k0 + scol, &Bb[s][r * 64]);
        }
    };

    int nk = K >> 6;
    stage(0, 0);
    asm volatile("s_waitcnt vmcnt(0)" ::: "memory");
    __builtin_amdgcn_s_barrier();

    for (int t = 0; t < nk; ++t) {
        int cur = t & 1;
        if (t + 1 < nk) stage(cur ^ 1, (t + 1) * 64);
#pragma unroll
        for (int ks = 0; ks < 2; ++ks) {
            int kk = ks * 32 + fk;
            bf16x8 af[MI], bfr[2];
#pragma unroll
            for (int i = 0; i < MI; ++i)
                af[i] = *(const bf16x8*)&Ab[cur][(wm + i * 16 + fr) * 64 + kk];
#pragma unroll
            for (int j = 0; j < 2; ++j)
                bfr[j] = *(const bf16x8*)&Bb[cur][(wn + j * 16 + fr) * 64 + kk];
#pragma unroll
            for (int i = 0; i < MI; ++i)
#pragma unroll
                for (int j = 0; j < 2; ++j)
                    acc[i][j] = __builtin_amdgcn_mfma_f32_16x16x32_bf16(
                        af[i], bfr[j], acc[i][j], 0, 0, 0);
        }
        asm volatile("s_waitcnt vmcnt(0)" ::: "memory");
        __builtin_amdgcn_s_barrier();
    }

#pragma unroll
    for (int i = 0; i < MI; ++i) {
#pragma unroll
        for (int j = 0; j < 2; ++j) {
            int lc = wn + j * 16 + fr;   // local col (token within tile for 0/1/2)
#pragma unroll
            for (int q = 0; q < 4; ++q) {
                int lr = wm + i * 16 + fq * 4 + q;   // local row
                float v = acc[i][j][q];
                if (MODE == 0) {
                    o0[(size_t)(bm + lr) * NTOK + bn + lc] = v;
                } else if (MODE == 1) {
                    int f = bm + lr;
                    if (f < 80) o0[(size_t)f * NTOK + bn + lc] = v;
                    Tt[lc * 64 + lr] = v;
                } else if (MODE == 2) {
                    float s = v + bias[bm + lr];
                    s = (s > 0.f) ? s + log1pf(__expf(-s)) : log1pf(__expf(s));
                    o0[(size_t)(bm + lr) * NTOK + bn + lc] = s;
                } else {  // MODE 3: residual accumulate + bf16 mirror
                    size_t idx = (size_t)(bm + lr) * DMODEL + bn + lc;
                    float nv = o0[idx] + v;
                    o0[idx] = nv;
                    o1[idx] = f2b(nv);
                }
            }
        }
    }
    if (MODE == 1) {
        __syncthreads();
        if (bm == 0) {   // rows 0..63 = dt-features (48) + B (16, don't-care for dt GEMM)
            int tok = tid >> 2;
            int fb = (tid & 3) * 16;
#pragma unroll
            for (int vv = 0; vv < 4; ++vv) {
                int f0 = fb + vv * 4;
                ushort4 o;
                o.x = f2b(Tt[tok * 64 + f0 + 0]);
                o.y = f2b(Tt[tok * 64 + f0 + 1]);
                o.z = f2b(Tt[tok * 64 + f0 + 2]);
                o.w = f2b(Tt[tok * 64 + f0 + 3]);
                *(ushort4*)(o1 + (size_t)(bn + tok) * 64 + f0) = o;
            }
        }
    }
}

// ---------------- causal dwconv(K=4) + bias + SiLU ----------------
__global__ __launch_bounds__(256) void conv_k(const float* __restrict__ xzT,
                                              const float* __restrict__ cw,
                                              const float* __restrict__ cb,
                                              float* __restrict__ xiT,
                                              unsigned short* __restrict__ xib) {
    __shared__ unsigned short tile[4][256];
    int tid = threadIdx.x;
    int ch = tid >> 6;
    int d = blockIdx.x * 4 + ch;
    int b = blockIdx.y;
    int t0 = (tid & 63) * 4;
    const float* src = xzT + (size_t)d * NTOK + b * TLEN + t0;
    float4 cur = *(const float4*)src;
    float4 prev = {0.f, 0.f, 0.f, 0.f};
    if (t0 > 0) prev = *(const float4*)(src - 4);
    float w0 = cw[d * 4 + 0], w1 = cw[d * 4 + 1], w2 = cw[d * 4 + 2], w3 = cw[d * 4 + 3];
    float bb = cb[d];
    float xw[8] = {prev.x, prev.y, prev.z, prev.w, cur.x, cur.y, cur.z, cur.w};
    float4 r;
#pragma unroll
    for (int u = 0; u < 4; ++u) {
        float s = bb + w0 * xw[u + 1] + w1 * xw[u + 2] + w2 * xw[u + 3] + w3 * xw[u + 4];
        float v = s / (1.f + __expf(-s));
        ((float*)&r)[u] = v;
        tile[ch][t0 + u] = f2b(v);
    }
    *(float4*)(xiT + (size_t)d * NTOK + b * TLEN + t0) = r;
    __syncthreads();
    int t = tid;
    ushort4 o;
    o.x = tile[0][t]; o.y = tile[1][t]; o.z = tile[2][t]; o.w = tile[3][t];
    *(ushort4*)(xib + (size_t)(b * TLEN + t) * DINNER + blockIdx.x * 4) = o;
}

// ---------------- selective scan, 8 waves = 8 time-chunks of 32 ----------------
// grid (DINNER/4 = 384, BATCH), 512 threads; wave: 4 chains x 16 states.
__global__ __launch_bounds__(512) void scan_k(const float* __restrict__ dtT,
                                              const float* __restrict__ xiT,
                                              const float* __restrict__ xzT,
                                              const float* __restrict__ xdblT,
                                              const float* __restrict__ Alog,
                                              const float* __restrict__ Dsk,
                                              unsigned short* __restrict__ ybb) {
    __shared__ float yl[4][260];
    __shared__ float cum[4][260];
    __shared__ float hL[8][4][16];
    __shared__ float Pb[8][4][16];
    __shared__ float Hin[8][4][16];

    int tid = threadIdx.x;
    int c = tid >> 6;            // time chunk 0..7
    int lane = tid & 63;
    int ch = lane >> 4;          // chain 0..3
    int n = lane & 15;           // state
    int d = blockIdx.x * 4 + ch;
    int b = blockIdx.y;
    int tl0 = c * 32;

    float a = -__expf(Alog[(size_t)d * NSTATE + n]);
    float Dv = Dsk[d];
    const float* dtp = dtT + (size_t)d * NTOK + b * TLEN + tl0;
    const float* xip = xiT + (size_t)d * NTOK + b * TLEN + tl0;
    const float* Bp = xdblT + (size_t)(DTRANK + n) * NTOK + b * TLEN + tl0;
    const float* Cp = xdblT + (size_t)(DTRANK + NSTATE + n) * NTOK + b * TLEN + tl0;

    float h = 0.f, cd = 0.f;
    for (int t8 = 0; t8 < 32; t8 += 8) {
        float4 d0 = *(const float4*)(dtp + t8), d1 = *(const float4*)(dtp + t8 + 4);
        float4 x0 = *(const float4*)(xip + t8), x1 = *(const float4*)(xip + t8 + 4);
        float4 B0 = *(const float4*)(Bp + t8), B1 = *(const float4*)(Bp + t8 + 4);
        float4 C0 = *(const float4*)(Cp + t8), C1 = *(const float4*)(Cp + t8 + 4);
        float dts[8] = {d0.x, d0.y, d0.z, d0.w, d1.x, d1.y, d1.z, d1.w};
        float xis[8] = {x0.x, x0.y, x0.z, x0.w, x1.x, x1.y, x1.z, x1.w};
        float Bs[8] = {B0.x, B0.y, B0.z, B0.w, B1.x, B1.y, B1.z, B1.w};
        float Cs[8] = {C0.x, C0.y, C0.z, C0.w, C1.x, C1.y, C1.z, C1.w};
#pragma unroll
        for (int u = 0; u < 8; ++u) {
            cd += dts[u];
            float dA = __expf(dts[u] * a);
            h = dA * h + (dts[u] * xis[u]) * Bs[u];
            float p = h * Cs[u];
            p += __shfl_xor(p, 1);
            p += __shfl_xor(p, 2);
            p += __shfl_xor(p, 4);
            p += __shfl_xor(p, 8);
            if (n == 0) {
                yl[ch][tl0 + t8 + u] = p + Dv * xis[u];   // D*xi folded into pass 1
                cum[ch][tl0 + t8 + u] = cd;
            }
        }
    }
    hL[c][ch][n] = h;
    Pb[c][ch][n] = __expf(a * cd);
    __syncthreads();
    if (c == 0) {   // serial carry chain over 8 chunks
        float H = 0.f;
        Hin[0][ch][n] = 0.f;
#pragma unroll
        for (int cc = 1; cc < 8; ++cc) {
            H = Pb[cc - 1][ch][n] * H + hL[cc - 1][ch][n];
            Hin[cc][ch][n] = H;
        }
    }
    __syncthreads();
    float Hv = Hin[c][ch][n];
    const float* zp = xzT + (size_t)(DINNER + d) * NTOK + b * TLEN + tl0;
    for (int t8 = 0; t8 < 32; t8 += 8) {
        float4 C0 = *(const float4*)(Cp + t8), C1 = *(const float4*)(Cp + t8 + 4);
        float4 z0 = *(const float4*)(zp + t8), z1 = *(const float4*)(zp + t8 + 4);
        float Cs[8] = {C0.x, C0.y, C0.z, C0.w, C1.x, C1.y, C1.z, C1.w};
        float zs[8] = {z0.x, z0.y, z0.z, z0.w, z1.x, z1.y, z1.z, z1.w};
#pragma unroll
        for (int u = 0; u < 8; ++u) {
            float cdt = cum[ch][tl0 + t8 + u];
            float corr = Cs[u] * __expf(a * cdt) * Hv;
            corr += __shfl_xor(corr, 1);
            corr += __shfl_xor(corr, 2);
            corr += __shfl_xor(corr, 4);
            corr += __shfl_xor(corr, 8);
            if (n == 0) {
                float y = yl[ch][tl0 + t8 + u] + corr;
                float zz = zs[u];
                y *= zz / (1.f + __expf(-zz));
                yl[ch][tl0 + t8 + u] = y;
            }
        }
    }
    __syncthreads();
    if (tid < 256) {
        int t = tid;
        ushort4 o;
        o.x = f2b(yl[0][t]);
        o.y = f2b(yl[1][t]);
        o.z = f2b(yl[2][t]);
        o.w = f2b(yl[3][t]);
        *(ushort4*)(ybb + (size_t)(b * TLEN + t) * DINNER + blockIdx.x * 4) = o;
    }
}

// ---------------- RMSNorm ----------------
__global__ __launch_bounds__(256) void rmsnorm_k(const float* __restrict__ x,
                                                 const float* __restrict__ nw,
                                                 float* __restrict__ out) {
    int row = blockIdx.x;
    const float* xr = x + (size_t)row * DMODEL;
    int tid = threadIdx.x;
    float s = 0.f;
    for (int d = tid; d < DMODEL; d += 256) {
        float v = xr[d];
        s += v * v;
    }
#pragma unroll
    for (int off = 32; off >= 1; off >>= 1) s += __shfl_down(s, off);
    __shared__ float red[4];
    __shared__ float scale;
    int wid = tid >> 6, lane = tid & 63;
    if (lane == 0) red[wid] = s;
    __syncthreads();
    if (tid == 0) {
        float tot = red[0] + red[1] + red[2] + red[3];
        scale = rsqrtf(tot / (float)DMODEL + 1e-5f);
    }
    __syncthreads();
    float sc = scale;
    for (int d = tid; d < DMODEL; d += 256)
        out[(size_t)row * DMODEL + d] = xr[d] * sc * nw[d];
}

extern "C" void kernel_launch(void* const* d_in, const int* in_sizes, int n_in,
                              void* d_out, int out_size, void* d_ws, size_t ws_size,
                              hipStream_t stream) {
    const int* ids = (const int*)d_in[0];
    const float* emb = (const float*)d_in[1];
    const float* pos = (const float*)d_in[2];
    const float* ipw = (const float*)d_in[3];
    const float* cw = (const float*)d_in[4];
    const float* cb = (const float*)d_in[5];
    const float* xpw = (const float*)d_in[6];
    const float* dpw = (const float*)d_in[7];
    const float* dpb = (const float*)d_in[8];
    const float* Alog = (const float*)d_in[9];
    const float* Dsk = (const float*)d_in[10];
    const float* opw = (const float*)d_in[11];
    const float* nw = (const float*)d_in[12];

    float* x = (float*)d_ws;                   // 786432
    float* xzT = x + 786432;                   // 3145728
    float* xiT = xzT + 3145728;                // 1572864
    float* xdblT = xiT + 1572864;              // 81920
    float* dtT = xdblT + 81920;                // 1572864
    unsigned short* xb = (unsigned short*)(dtT + 1572864);  // 786432
    unsigned short* xib = xb + 786432;         // 1572864
    unsigned short* ybb = xib + 1572864;       // 1572864
    unsigned short* xdblb = ybb + 1572864;     // 65536
    unsigned short* w_all = xdblb + 65536;     // 4 * WL

    wconv_k<<<dim3(WL / 1024, NLAYER), 256, 0, stream>>>(ipw, opw, xpw, dpw, w_all);
    embed_k<<<NTOK * DMODEL / 256, 256, 0, stream>>>(ids, emb, pos, x, xb);

    for (int l = 0; l < NLAYER; ++l) {
        const unsigned short* w_ip = w_all + (size_t)l * WL;
        const unsigned short* w_op = w_ip + S_IP;
        const unsigned short* w_xp = w_op + S_OP;
        const unsigned short* w_dt = w_xp + S_XP2;
        const float* cw_l = cw + (size_t)l * DINNER * 4;
        const float* cb_l = cb + (size_t)l * DINNER;
        const float* dpb_l = dpb + (size_t)l * DINNER;
        const float* Alog_l = Alog + (size_t)l * DINNER * NSTATE;
        const float* Dsk_l = Dsk + (size_t)l * DINNER;

        // in_proj: xzT[e][tok]
        mgemm_k<128, 0><<<dim3(3072 / 128, NTOK / 64), 256, 0, stream>>>(
            w_ip, DMODEL, xb, DMODEL, DMODEL, nullptr, xzT, nullptr);
        // conv + silu -> xiT f32, xib bf16
        conv_k<<<dim3(DINNER / 4, BATCH), 256, 0, stream>>>(xzT, cw_l, cb_l, xiT, xib);
        // x_proj: xdblT [80][1024] f32 + xdblb bf16 [1024][64]
        mgemm_k<64, 1><<<dim3(2, NTOK / 64), 256, 0, stream>>>(
            w_xp, DINNER, xib, DINNER, DINNER, nullptr, xdblT, xdblb);
        // dt_proj: dtT[d][tok] = softplus(. + dpb), K=64
        mgemm_k<128, 2><<<dim3(DINNER / 128, NTOK / 64), 256, 0, stream>>>(
            w_dt, 64, xdblb, 64, 64, dpb_l, dtT, nullptr);
        // scan
        scan_k<<<dim3(DINNER / 4, BATCH), 512, 0, stream>>>(
            dtT, xiT, xzT, xdblT, Alog_l, Dsk_l, ybb);
        // out_proj: x += y @ opw^T, xb = bf16(x)
        mgemm_k<128, 3><<<dim3(NTOK / 128, DMODEL / 64), 256, 0, stream>>>(
            ybb, DINNER, w_op, DINNER, DINNER, nullptr, x, xb);
    }

    rmsnorm_k<<<NTOK, 256, 0, stream>>>(x, nw, (float*)d_out);
}

// Round 7
// 527.207 us; speedup vs baseline: 2.1348x; 1.1450x over previous
//
#include <hip/hip_runtime.h>
#include <math.h>

#define TLEN 256
#define BATCH 4
#define DMODEL 768
#define DINNER 1536
#define NSTATE 16
#define DTRANK 48
#define NLAYER 4
#define NTOK 1024

#define S_IP 2359296
#define S_OP 1179648
#define S_XP2 196608            /* 128 x 1536 zero-padded */
#define S_DT 98304              /* 1536 x 64 zero-padded  */
#define WL (S_IP + S_OP + S_XP2 + S_DT)

typedef __bf16 bf16x8 __attribute__((ext_vector_type(8)));
typedef float f32x4 __attribute__((ext_vector_type(4)));

__device__ inline unsigned short f2b(float f) {
    union { float f; unsigned u; } v;
    v.f = f;
    unsigned r = (v.u + 0x7fffu + ((v.u >> 16) & 1u)) >> 16;  // RNE
    return (unsigned short)r;
}

__device__ inline void gload16(const void* g, void* l) {
    __builtin_amdgcn_global_load_lds(
        (const __attribute__((address_space(1))) void*)g,
        (__attribute__((address_space(3))) void*)l, 16, 0, 0);
}

// 16-lane sum via DPP (quad xor1, xor2, then row_ror 4, 8) — no DS ops.
__device__ inline float red16(float p) {
    p += __int_as_float(__builtin_amdgcn_update_dpp(0, __float_as_int(p), 0xB1, 0xf, 0xf, true));
    p += __int_as_float(__builtin_amdgcn_update_dpp(0, __float_as_int(p), 0x4E, 0xf, 0xf, true));
    p += __int_as_float(__builtin_amdgcn_update_dpp(0, __float_as_int(p), 0x124, 0xf, 0xf, true));
    p += __int_as_float(__builtin_amdgcn_update_dpp(0, __float_as_int(p), 0x128, 0xf, 0xf, true));
    return p;
}

// ---------------- embed: f32 x + bf16 xb ----------------
__global__ __launch_bounds__(256) void embed_k(const int* __restrict__ ids,
                                               const float* __restrict__ emb,
                                               const float* __restrict__ pos,
                                               float* __restrict__ x,
                                               unsigned short* __restrict__ xb) {
    int idx = blockIdx.x * 256 + threadIdx.x;
    int d = idx % DMODEL;
    int bt = idx / DMODEL;
    int t = bt % TLEN;
    float v = emb[(size_t)ids[bt] * DMODEL + d] + pos[t * DMODEL + d];
    x[idx] = v;
    xb[idx] = f2b(v);
}

// ---------------- all-layer weight convert (ip, op, xp-pad128, dt-pad64) ----------------
__global__ __launch_bounds__(256) void wconv_k(const float* __restrict__ ipw,
                                               const float* __restrict__ opw,
                                               const float* __restrict__ xpw,
                                               const float* __restrict__ dpw,
                                               unsigned short* __restrict__ w_all) {
    int l = blockIdx.y;
    int i4 = (blockIdx.x * 256 + threadIdx.x) * 4;
    unsigned short* wl = w_all + (size_t)l * WL;
    if (i4 < S_IP) {
        float4 v = *(const float4*)(ipw + (size_t)l * S_IP + i4);
        ushort4 o; o.x = f2b(v.x); o.y = f2b(v.y); o.z = f2b(v.z); o.w = f2b(v.w);
        *(ushort4*)(wl + i4) = o;
    } else if (i4 < S_IP + S_OP) {
        int i = i4 - S_IP;
        float4 v = *(const float4*)(opw + (size_t)l * S_OP + i);
        ushort4 o; o.x = f2b(v.x); o.y = f2b(v.y); o.z = f2b(v.z); o.w = f2b(v.w);
        *(ushort4*)(wl + S_IP + i) = o;
    } else if (i4 < S_IP + S_OP + S_XP2) {
        int i = i4 - S_IP - S_OP;
        int r = i / 1536, k = i % 1536;
        ushort4 o = {0, 0, 0, 0};
        if (r < 80) {
            float4 v = *(const float4*)(xpw + (size_t)l * (80 * 1536) + (size_t)r * 1536 + k);
            o.x = f2b(v.x); o.y = f2b(v.y); o.z = f2b(v.z); o.w = f2b(v.w);
        }
        *(ushort4*)(wl + S_IP + S_OP + i) = o;
    } else {
        int i = i4 - S_IP - S_OP - S_XP2;
        int r = i >> 6, k = i & 63;
        ushort4 o = {0, 0, 0, 0};
        if (k < DTRANK) {
            float4 v = *(const float4*)(dpw + (size_t)l * (DINNER * DTRANK) + (size_t)r * DTRANK + k);
            o.x = f2b(v.x); o.y = f2b(v.y); o.z = f2b(v.z); o.w = f2b(v.w);
        }
        *(ushort4*)(wl + S_IP + S_OP + S_XP2 + i) = o;
    }
}

// ---------------- bf16 MFMA GEMM, 2-phase LDS double-buffer, BM=64 tiles ----------------
// D[row][col] = sum_k A[row,k]*B[col,k]; A,B bf16 row-major (k contiguous).
// MODE 0: o0 = xzT [3072][1024] f32 (rows=e, cols=tok)                  (in_proj)
// MODE 1: o0 = xdblT [80][1024] f32 (rows<80); o1 = xdblb bf16 [1024][64]
//         via LDS transpose, bm==0 blocks only                          (x_proj)
// MODE 2: o0 = dtT [1536][1024] f32, softplus(v + bias[row])            (dt_proj)
// MODE 3: o0 = x [1024][768] f32 accumulate, o1 = xb bf16 mirror        (out_proj)
template <int BM, int MODE>
__global__ __launch_bounds__(256) void mgemm_k(const unsigned short* __restrict__ A, int lda,
                                               const unsigned short* __restrict__ B, int ldb,
                                               int K,
                                               const float* __restrict__ bias,
                                               float* __restrict__ o0,
                                               unsigned short* __restrict__ o1) {
    constexpr int MI = BM / 32;
    __shared__ __align__(16) unsigned short Ab[2][BM * 64];
    __shared__ __align__(16) unsigned short Bb[2][64 * 64];
    __shared__ float Tt[(MODE == 1) ? 64 * 64 : 1];

    int tid = threadIdx.x;
    int lane = tid & 63;
    int wave = tid >> 6;
    int wm = (wave >> 1) * (BM / 2);
    int wn = (wave & 1) * 32;
    int bm = blockIdx.x * BM;
    int bn = blockIdx.y * 64;
    int fr = lane & 15;
    int fq = lane >> 4;
    int fk = fq * 8;
    int srow = lane >> 3;        // 0..7
    int scol = (lane & 7) * 8;   // 0..56 (elems)

    f32x4 acc[MI][2] = {};

    auto stage = [&](int s, int k0) {
#pragma unroll
        for (int c = 0; c < BM / 32; ++c) {   // A: 8 rows per gload
            int r = wave * (BM / 4) + c * 8;
            gload16(A + (size_t)(bm + r + srow) * lda + k0 + scol, &Ab[s][r * 64]);
        }
#pragma unroll
        for (int c = 0; c < 2; ++c) {         // B: 16 rows per wave
            int r = wave * 16 + c * 8;
            gload16(B + (size_t)(bn + r + srow) * ldb + k0 + scol, &Bb[s][r * 64]);
        }
    };

    int nk = K >> 6;
    stage(0, 0);
    asm volatile("s_waitcnt vmcnt(0)" ::: "memory");
    __builtin_amdgcn_s_barrier();

    for (int t = 0; t < nk; ++t) {
        int cur = t & 1;
        if (t + 1 < nk) stage(cur ^ 1, (t + 1) * 64);
#pragma unroll
        for (int ks = 0; ks < 2; ++ks) {
            int kk = ks * 32 + fk;
            bf16x8 af[MI], bfr[2];
#pragma unroll
            for (int i = 0; i < MI; ++i)
                af[i] = *(const bf16x8*)&Ab[cur][(wm + i * 16 + fr) * 64 + kk];
#pragma unroll
            for (int j = 0; j < 2; ++j)
                bfr[j] = *(const bf16x8*)&Bb[cur][(wn + j * 16 + fr) * 64 + kk];
#pragma unroll
            for (int i = 0; i < MI; ++i)
#pragma unroll
                for (int j = 0; j < 2; ++j)
                    acc[i][j] = __builtin_amdgcn_mfma_f32_16x16x32_bf16(
                        af[i], bfr[j], acc[i][j], 0, 0, 0);
        }
        asm volatile("s_waitcnt vmcnt(0)" ::: "memory");
        __builtin_amdgcn_s_barrier();
    }

#pragma unroll
    for (int i = 0; i < MI; ++i) {
#pragma unroll
        for (int j = 0; j < 2; ++j) {
            int lc = wn + j * 16 + fr;   // local col (token within tile for 0/1/2)
#pragma unroll
            for (int q = 0; q < 4; ++q) {
                int lr = wm + i * 16 + fq * 4 + q;   // local row
                float v = acc[i][j][q];
                if (MODE == 0) {
                    o0[(size_t)(bm + lr) * NTOK + bn + lc] = v;
                } else if (MODE == 1) {
                    int f = bm + lr;
                    if (f < 80) o0[(size_t)f * NTOK + bn + lc] = v;
                    Tt[lc * 64 + lr] = v;
                } else if (MODE == 2) {
                    float s = v + bias[bm + lr];
                    s = (s > 0.f) ? s + log1pf(__expf(-s)) : log1pf(__expf(s));
                    o0[(size_t)(bm + lr) * NTOK + bn + lc] = s;
                } else {  // MODE 3: residual accumulate + bf16 mirror
                    size_t idx = (size_t)(bm + lr) * DMODEL + bn + lc;
                    float nv = o0[idx] + v;
                    o0[idx] = nv;
                    o1[idx] = f2b(nv);
                }
            }
        }
    }
    if (MODE == 1) {
        __syncthreads();
        if (bm == 0) {   // rows 0..63 = dt-features (48) + B (16, zero-weighted in dt GEMM)
            int tok = tid >> 2;
            int fb = (tid & 3) * 16;
#pragma unroll
            for (int vv = 0; vv < 4; ++vv) {
                int f0 = fb + vv * 4;
                ushort4 o;
                o.x = f2b(Tt[tok * 64 + f0 + 0]);
                o.y = f2b(Tt[tok * 64 + f0 + 1]);
                o.z = f2b(Tt[tok * 64 + f0 + 2]);
                o.w = f2b(Tt[tok * 64 + f0 + 3]);
                *(ushort4*)(o1 + (size_t)(bn + tok) * 64 + f0) = o;
            }
        }
    }
}

// ---------------- causal dwconv(K=4) + bias + SiLU -> bf16 xib only ----------------
__global__ __launch_bounds__(256) void conv_k(const float* __restrict__ xzT,
                                              const float* __restrict__ cw,
                                              const float* __restrict__ cb,
                                              unsigned short* __restrict__ xib) {
    __shared__ unsigned short tile[4][256];
    int tid = threadIdx.x;
    int ch = tid >> 6;
    int d = blockIdx.x * 4 + ch;
    int b = blockIdx.y;
    int t0 = (tid & 63) * 4;
    const float* src = xzT + (size_t)d * NTOK + b * TLEN + t0;
    float4 cur = *(const float4*)src;
    float4 prev = {0.f, 0.f, 0.f, 0.f};
    if (t0 > 0) prev = *(const float4*)(src - 4);
    float w0 = cw[d * 4 + 0], w1 = cw[d * 4 + 1], w2 = cw[d * 4 + 2], w3 = cw[d * 4 + 3];
    float bb = cb[d];
    float xw[8] = {prev.x, prev.y, prev.z, prev.w, cur.x, cur.y, cur.z, cur.w};
#pragma unroll
    for (int u = 0; u < 4; ++u) {
        float s = bb + w0 * xw[u + 1] + w1 * xw[u + 2] + w2 * xw[u + 3] + w3 * xw[u + 4];
        float v = s / (1.f + __expf(-s));
        tile[ch][t0 + u] = f2b(v);
    }
    __syncthreads();
    int t = tid;
    ushort4 o;
    o.x = tile[0][t]; o.y = tile[1][t]; o.z = tile[2][t]; o.w = tile[3][t];
    *(ushort4*)(xib + (size_t)(b * TLEN + t) * DINNER + blockIdx.x * 4) = o;
}

// ---------------- selective scan, 8 waves x 32-step chunks, DPP reduce, inline conv ----
// grid (DINNER/4 = 384, BATCH), 512 threads; wave: 4 chains x 16 states.
__global__ __launch_bounds__(512) void scan_k(const float* __restrict__ dtT,
                                              const float* __restrict__ xzT,
                                              const float* __restrict__ xdblT,
                                              const float* __restrict__ cw,
                                              const float* __restrict__ cb,
                                              const float* __restrict__ Alog,
                                              const float* __restrict__ Dsk,
                                              unsigned short* __restrict__ ybb) {
    __shared__ float yl[4][260];
    __shared__ float cum[4][260];
    __shared__ float hL[8][4][16];
    __shared__ float Pb[8][4][16];
    __shared__ float Hin[8][4][16];

    int tid = threadIdx.x;
    int c = tid >> 6;            // time chunk 0..7
    int lane = tid & 63;
    int ch = lane >> 4;          // chain 0..3
    int n = lane & 15;           // state
    int d = blockIdx.x * 4 + ch;
    int b = blockIdx.y;
    int tl0 = c * 32;

    float a = -__expf(Alog[(size_t)d * NSTATE + n]);
    float Dv = Dsk[d];
    float w0 = cw[d * 4 + 0], w1 = cw[d * 4 + 1], w2 = cw[d * 4 + 2], w3 = cw[d * 4 + 3];
    float cbv = cb[d];
    const float* dtp = dtT + (size_t)d * NTOK + b * TLEN + tl0;
    const float* xzp = xzT + (size_t)d * NTOK + b * TLEN + tl0;     // x-part row d
    const float* Bp = xdblT + (size_t)(DTRANK + n) * NTOK + b * TLEN + tl0;
    const float* Cp = xdblT + (size_t)(DTRANK + NSTATE + n) * NTOK + b * TLEN + tl0;

    // conv history xz[t0-3..t0-1]
    float hm3 = 0.f, hm2 = 0.f, hm1 = 0.f;
    if (tl0 > 0) {
        float4 pv = *(const float4*)(xzp - 4);
        hm3 = pv.y; hm2 = pv.z; hm1 = pv.w;
    }

    float h = 0.f, cd = 0.f;
    for (int t8 = 0; t8 < 32; t8 += 8) {
        float4 d0 = *(const float4*)(dtp + t8), d1 = *(const float4*)(dtp + t8 + 4);
        float4 x0 = *(const float4*)(xzp + t8), x1 = *(const float4*)(xzp + t8 + 4);
        float4 B0 = *(const float4*)(Bp + t8), B1 = *(const float4*)(Bp + t8 + 4);
        float4 C0 = *(const float4*)(Cp + t8), C1 = *(const float4*)(Cp + t8 + 4);
        float dts[8] = {d0.x, d0.y, d0.z, d0.w, d1.x, d1.y, d1.z, d1.w};
        float xw[11] = {hm3, hm2, hm1, x0.x, x0.y, x0.z, x0.w, x1.x, x1.y, x1.z, x1.w};
        float Bs[8] = {B0.x, B0.y, B0.z, B0.w, B1.x, B1.y, B1.z, B1.w};
        float Cs[8] = {C0.x, C0.y, C0.z, C0.w, C1.x, C1.y, C1.z, C1.w};
#pragma unroll
        for (int u = 0; u < 8; ++u) {
            float s = cbv + w0 * xw[u] + w1 * xw[u + 1] + w2 * xw[u + 2] + w3 * xw[u + 3];
            float xi = s / (1.f + __expf(-s));          // conv + SiLU recompute (f32)
            float dtv = dts[u];
            cd += dtv;
            float dA = __expf(dtv * a);
            h = dA * h + (dtv * xi) * Bs[u];
            float p = red16(h * Cs[u]);
            if (n == 0) {
                yl[ch][tl0 + t8 + u] = p + Dv * xi;     // D*xi folded into pass 1
                cum[ch][tl0 + t8 + u] = cd;
            }
        }
        hm3 = xw[8]; hm2 = xw[9]; hm1 = xw[10];
    }
    hL[c][ch][n] = h;
    Pb[c][ch][n] = __expf(a * cd);
    __syncthreads();
    if (c == 0) {   // serial carry chain over 8 chunks
        float H = 0.f;
        Hin[0][ch][n] = 0.f;
#pragma unroll
        for (int cc = 1; cc < 8; ++cc) {
            H = Pb[cc - 1][ch][n] * H + hL[cc - 1][ch][n];
            Hin[cc][ch][n] = H;
        }
    }
    __syncthreads();
    float Hv = Hin[c][ch][n];
    const float* zp = xzT + (size_t)(DINNER + d) * NTOK + b * TLEN + tl0;
    for (int t8 = 0; t8 < 32; t8 += 8) {
        float4 C0 = *(const float4*)(Cp + t8), C1 = *(const float4*)(Cp + t8 + 4);
        float4 z0 = *(const float4*)(zp + t8), z1 = *(const float4*)(zp + t8 + 4);
        float Cs[8] = {C0.x, C0.y, C0.z, C0.w, C1.x, C1.y, C1.z, C1.w};
        float zs[8] = {z0.x, z0.y, z0.z, z0.w, z1.x, z1.y, z1.z, z1.w};
#pragma unroll
        for (int u = 0; u < 8; ++u) {
            float cdt = cum[ch][tl0 + t8 + u];
            float corr = red16(Cs[u] * __expf(a * cdt) * Hv);
            if (n == 0) {
                float y = yl[ch][tl0 + t8 + u] + corr;
                float zz = zs[u];
                y *= zz / (1.f + __expf(-zz));
                yl[ch][tl0 + t8 + u] = y;
            }
        }
    }
    __syncthreads();
    if (tid < 256) {
        int t = tid;
        ushort4 o;
        o.x = f2b(yl[0][t]);
        o.y = f2b(yl[1][t]);
        o.z = f2b(yl[2][t]);
        o.w = f2b(yl[3][t]);
        *(ushort4*)(ybb + (size_t)(b * TLEN + t) * DINNER + blockIdx.x * 4) = o;
    }
}

// ---------------- RMSNorm ----------------
__global__ __launch_bounds__(256) void rmsnorm_k(const float* __restrict__ x,
                                                 const float* __restrict__ nw,
                                                 float* __restrict__ out) {
    int row = blockIdx.x;
    const float* xr = x + (size_t)row * DMODEL;
    int tid = threadIdx.x;
    float s = 0.f;
    for (int d = tid; d < DMODEL; d += 256) {
        float v = xr[d];
        s += v * v;
    }
#pragma unroll
    for (int off = 32; off >= 1; off >>= 1) s += __shfl_down(s, off);
    __shared__ float red[4];
    __shared__ float scale;
    int wid = tid >> 6, lane = tid & 63;
    if (lane == 0) red[wid] = s;
    __syncthreads();
    if (tid == 0) {
        float tot = red[0] + red[1] + red[2] + red[3];
        scale = rsqrtf(tot / (float)DMODEL + 1e-5f);
    }
    __syncthreads();
    float sc = scale;
    for (int d = tid; d < DMODEL; d += 256)
        out[(size_t)row * DMODEL + d] = xr[d] * sc * nw[d];
}

extern "C" void kernel_launch(void* const* d_in, const int* in_sizes, int n_in,
                              void* d_out, int out_size, void* d_ws, size_t ws_size,
                              hipStream_t stream) {
    const int* ids = (const int*)d_in[0];
    const float* emb = (const float*)d_in[1];
    const float* pos = (const float*)d_in[2];
    const float* ipw = (const float*)d_in[3];
    const float* cw = (const float*)d_in[4];
    const float* cb = (const float*)d_in[5];
    const float* xpw = (const float*)d_in[6];
    const float* dpw = (const float*)d_in[7];
    const float* dpb = (const float*)d_in[8];
    const float* Alog = (const float*)d_in[9];
    const float* Dsk = (const float*)d_in[10];
    const float* opw = (const float*)d_in[11];
    const float* nw = (const float*)d_in[12];

    float* x = (float*)d_ws;                   // 786432
    float* xzT = x + 786432;                   // 3145728
    float* xdblT = xzT + 3145728;              // 81920
    float* dtT = xdblT + 81920;                // 1572864
    unsigned short* xb = (unsigned short*)(dtT + 1572864);  // 786432
    unsigned short* xib = xb + 786432;         // 1572864
    unsigned short* ybb = xib + 1572864;       // 1572864
    unsigned short* xdblb = ybb + 1572864;     // 65536
    unsigned short* w_all = xdblb + 65536;     // 4 * WL

    wconv_k<<<dim3(WL / 1024, NLAYER), 256, 0, stream>>>(ipw, opw, xpw, dpw, w_all);
    embed_k<<<NTOK * DMODEL / 256, 256, 0, stream>>>(ids, emb, pos, x, xb);

    for (int l = 0; l < NLAYER; ++l) {
        const unsigned short* w_ip = w_all + (size_t)l * WL;
        const unsigned short* w_op = w_ip + S_IP;
        const unsigned short* w_xp = w_op + S_OP;
        const unsigned short* w_dt = w_xp + S_XP2;
        const float* cw_l = cw + (size_t)l * DINNER * 4;
        const float* cb_l = cb + (size_t)l * DINNER;
        const float* dpb_l = dpb + (size_t)l * DINNER;
        const float* Alog_l = Alog + (size_t)l * DINNER * NSTATE;
        const float* Dsk_l = Dsk + (size_t)l * DINNER;

        // in_proj: xzT[e][tok], 768 blocks (3/CU)
        mgemm_k<64, 0><<<dim3(3072 / 64, NTOK / 64), 256, 0, stream>>>(
            w_ip, DMODEL, xb, DMODEL, DMODEL, nullptr, xzT, nullptr);
        // conv + silu -> xib bf16 (x_proj operand only)
        conv_k<<<dim3(DINNER / 4, BATCH), 256, 0, stream>>>(xzT, cw_l, cb_l, xib);
        // x_proj: xdblT [80][1024] f32 + xdblb bf16 [1024][64]
        mgemm_k<64, 1><<<dim3(2, NTOK / 64), 256, 0, stream>>>(
            w_xp, DINNER, xib, DINNER, DINNER, nullptr, xdblT, xdblb);
        // dt_proj: dtT[d][tok] = softplus(. + dpb), K=64
        mgemm_k<64, 2><<<dim3(DINNER / 64, NTOK / 64), 256, 0, stream>>>(
            w_dt, 64, xdblb, 64, 64, dpb_l, dtT, nullptr);
        // scan (inline conv recompute + DPP reduce)
        scan_k<<<dim3(DINNER / 4, BATCH), 512, 0, stream>>>(
            dtT, xzT, xdblT, cw_l, cb_l, Alog_l, Dsk_l, ybb);
        // out_proj: x += y @ opw^T, xb = bf16(x), 192 blocks
        mgemm_k<64, 3><<<dim3(NTOK / 64, DMODEL / 64), 256, 0, stream>>>(
            ybb, DINNER, w_op, DINNER, DINNER, nullptr, x, xb);
    }

    rmsnorm_k<<<NTOK, 256, 0, stream>>>(x, nw, (float*)d_out);
}